// Round 3
// baseline (108.466 us; speedup 1.0000x reference)
//
#include <hip/hip_runtime.h>

// result = sum_{b,s,c,h,w} visweight[b,s,h,w] * (conv - out)^2 / 1024
// output/convdata [8,300,4,32,32] f32 (2,457,600 float4), visweight [8,300,32,32].
//
// Tiling: 2,457,600 float4 = 2400 blocks x 256 threads x 4 float4.
// Each block covers exactly ONE (b,s) slab (4 channels x 256 float4):
//   flat f4 index i = blk*1024 + u*256 + t  ->  bs = blk, hw4 = t.
// -> ONE weight float4 per thread, reused across all 4 channels.
//
// Two-stage reduction, no atomics (round-1: 2048 same-address atomicAdds
// serialized ~40 us: VALU 3%, HBM 17%).
// Harness fixed overhead (d_ws 268MB 0xAA poison + d_in restore) ~86 us of
// dur_us is outside kernel control; controllable floor = 88.5 MB / 6.3 TB/s
// ~ 14 us (ws-poison evicts inputs from L3, so HBM-fed).

#define NBLK 2400

__global__ __launch_bounds__(256) void loss_stage1(
    const float4* __restrict__ outp,
    const float4* __restrict__ conv,
    const float4* __restrict__ wgt,
    float* __restrict__ partial)
{
    const int t = threadIdx.x;
    const int base = blockIdx.x * 1024 + t;

    // 9 independent 16B loads in flight per thread.
    float4 o[4], c[4];
    #pragma unroll
    for (int u = 0; u < 4; ++u) {
        o[u] = outp[base + u * 256];
        c[u] = conv[base + u * 256];
    }
    const float4 w = wgt[blockIdx.x * 256 + t];

    float acc0 = 0.f, acc1 = 0.f;
    #pragma unroll
    for (int u = 0; u < 4; ++u) {
        const float dx = c[u].x - o[u].x;
        const float dy = c[u].y - o[u].y;
        const float dz = c[u].z - o[u].z;
        const float dw = c[u].w - o[u].w;
        if (u & 1)
            acc1 += w.x * dx * dx + w.y * dy * dy + w.z * dz * dz + w.w * dw * dw;
        else
            acc0 += w.x * dx * dx + w.y * dy * dy + w.z * dz * dz + w.w * dw * dw;
    }
    float acc = acc0 + acc1;

    // 64-lane wave reduction
    #pragma unroll
    for (int off = 32; off > 0; off >>= 1)
        acc += __shfl_down(acc, off, 64);

    __shared__ float sbuf[4];
    const int lane = t & 63;
    const int wid  = t >> 6;
    if (lane == 0) sbuf[wid] = acc;
    __syncthreads();
    if (t == 0)
        partial[blockIdx.x] = (sbuf[0] + sbuf[1]) + (sbuf[2] + sbuf[3]);
}

__global__ __launch_bounds__(256) void loss_stage2(
    const float* __restrict__ partial,
    float* __restrict__ result)
{
    const int t = threadIdx.x;
    float acc = 0.f;
    #pragma unroll 4
    for (int i = t; i < NBLK; i += 256) acc += partial[i];

    #pragma unroll
    for (int off = 32; off > 0; off >>= 1)
        acc += __shfl_down(acc, off, 64);

    __shared__ float sbuf[4];
    const int lane = t & 63;
    const int wid  = t >> 6;
    if (lane == 0) sbuf[wid] = acc;
    __syncthreads();
    if (t == 0)
        result[0] = ((sbuf[0] + sbuf[1]) + (sbuf[2] + sbuf[3])) * (1.0f / 1024.0f);
}

extern "C" void kernel_launch(void* const* d_in, const int* in_sizes, int n_in,
                              void* d_out, int out_size, void* d_ws, size_t ws_size,
                              hipStream_t stream) {
    const float4* outp = (const float4*)d_in[0];  // output   [8,300,4,32,32]
    const float4* conv = (const float4*)d_in[1];  // convdata [8,300,4,32,32]
    const float4* wgt  = (const float4*)d_in[2];  // visweight[8,300,32,32]
    float* partial = (float*)d_ws;                // 2400 floats of scratch
    float* result  = (float*)d_out;

    loss_stage1<<<NBLK, 256, 0, stream>>>(outp, conv, wgt, partial);
    loss_stage2<<<1, 256, 0, stream>>>(partial, result);
}

// Round 5
// 105.224 us; speedup vs baseline: 1.0308x; 1.0308x over previous
//
#include <hip/hip_runtime.h>

// result = sum_{b,s,c,h,w} visweight[b,s,h,w] * (conv - out)^2 / 1024
// output/convdata [8,300,4,32,32] f32 (2,457,600 float4), visweight [8,300,32,32].
//
// Measured-best config (R2, 105.7 us): 1200 blocks x 256 threads x 8 float4.
// Per block: 2048 consecutive float4 = 2 (b,s)-slabs x 4 channels x 256:
//   i = blk*2048 + u*256 + t -> hw4 = t, bs = blk*2 + (u>>2)
// -> 2 weight float4 per thread; 18 independent 16B loads in flight.
//
// Two-stage reduction, no atomics (R1: 2048 same-address atomicAdds serialized
// ~40 us: VALU 3%, HBM 17%). R3 (2400x4 tiling) regressed -> reverted.
// R4 FAILED: stage2 launched with 320 threads > __launch_bounds__(256) ->
// silent launch failure, result stayed 0. Stage2 must use <=256 threads.
// Structural ceiling: 88.5 MB / 6.3 TB/s ~ 14 us stage1 (ws-poison evicts L3)
// + ~2-4 us stage2+launch; harness fixed overhead ~86 us dominates dur_us.

#define NBLK 1200

__global__ __launch_bounds__(256) void loss_stage1(
    const float4* __restrict__ outp,
    const float4* __restrict__ conv,
    const float4* __restrict__ wgt,
    float* __restrict__ partial)
{
    const int t = threadIdx.x;
    const int base = blockIdx.x * 2048 + t;

    float4 o[8], c[8];
    #pragma unroll
    for (int u = 0; u < 8; ++u) {
        o[u] = outp[base + u * 256];
        c[u] = conv[base + u * 256];
    }
    const int wbase = blockIdx.x * 512 + t;
    const float4 w0 = wgt[wbase];
    const float4 w1 = wgt[wbase + 256];

    float acc0 = 0.f, acc1 = 0.f;
    #pragma unroll
    for (int u = 0; u < 8; ++u) {
        const float4 w = (u < 4) ? w0 : w1;
        const float dx = c[u].x - o[u].x;
        const float dy = c[u].y - o[u].y;
        const float dz = c[u].z - o[u].z;
        const float dw = c[u].w - o[u].w;
        if (u & 1)
            acc1 += w.x * dx * dx + w.y * dy * dy + w.z * dz * dz + w.w * dw * dw;
        else
            acc0 += w.x * dx * dx + w.y * dy * dy + w.z * dz * dz + w.w * dw * dw;
    }
    float acc = acc0 + acc1;

    #pragma unroll
    for (int off = 32; off > 0; off >>= 1)
        acc += __shfl_down(acc, off, 64);

    __shared__ float sbuf[4];
    const int lane = t & 63;
    const int wid  = t >> 6;
    if (lane == 0) sbuf[wid] = acc;
    __syncthreads();
    if (t == 0)
        partial[blockIdx.x] = (sbuf[0] + sbuf[1]) + (sbuf[2] + sbuf[3]);
}

__global__ __launch_bounds__(256) void loss_stage2(
    const float4* __restrict__ partial4,   // 1200 floats = 300 float4
    float* __restrict__ result)
{
    const int t = threadIdx.x;  // 256 threads, 4 waves
    // threads 0..255 cover float4 [0,256); threads 0..43 also cover [256,300).
    float4 p = partial4[t];
    float acc = (p.x + p.y) + (p.z + p.w);
    if (t < 44) {
        const float4 q = partial4[t + 256];
        acc += (q.x + q.y) + (q.z + q.w);
    }

    #pragma unroll
    for (int off = 32; off > 0; off >>= 1)
        acc += __shfl_down(acc, off, 64);

    __shared__ float sbuf[4];
    const int lane = t & 63;
    const int wid  = t >> 6;
    if (lane == 0) sbuf[wid] = acc;
    __syncthreads();
    if (t == 0)
        result[0] = ((sbuf[0] + sbuf[1]) + (sbuf[2] + sbuf[3])) * (1.0f / 1024.0f);
}

extern "C" void kernel_launch(void* const* d_in, const int* in_sizes, int n_in,
                              void* d_out, int out_size, void* d_ws, size_t ws_size,
                              hipStream_t stream) {
    const float4* outp = (const float4*)d_in[0];  // output   [8,300,4,32,32]
    const float4* conv = (const float4*)d_in[1];  // convdata [8,300,4,32,32]
    const float4* wgt  = (const float4*)d_in[2];  // visweight[8,300,32,32]
    float* partial = (float*)d_ws;                // 1200 floats of scratch
    float* result  = (float*)d_out;

    loss_stage1<<<NBLK, 256, 0, stream>>>(outp, conv, wgt, partial);
    loss_stage2<<<1, 256, 0, stream>>>((const float4*)partial, result);
}